// Round 1
// baseline (345.515 us; speedup 1.0000x reference)
//
#include <hip/hip_runtime.h>

typedef unsigned short u16;
typedef __attribute__((ext_vector_type(8))) short short8;
typedef __attribute__((ext_vector_type(4))) float f32x4;

#define MFMA16(a, b, c) __builtin_amdgcn_mfma_f32_16x16x32_bf16(a, b, c, 0, 0, 0)

// B=2, S=2048, D=1024, H=16, KVH=4, dk=64, G=4
#define SEQ 2048
#define DM 1024

__device__ __forceinline__ u16 f2bf(float f) {
  unsigned u = __float_as_uint(f);
  u += 0x7fffu + ((u >> 16) & 1u);   // round-to-nearest-even
  return (u16)(u >> 16);
}

// ---------- fp32 -> bf16 elementwise ----------
__global__ void k_convert(const float* __restrict__ in, u16* __restrict__ out, int n) {
  for (int i = (blockIdx.x * 256 + threadIdx.x) * 4; i < n; i += gridDim.x * 256 * 4) {
    float4 f = *(const float4*)(in + i);
    uint2 o;
    o.x = (unsigned)f2bf(f.x) | ((unsigned)f2bf(f.y) << 16);
    o.y = (unsigned)f2bf(f.z) | ((unsigned)f2bf(f.w) << 16);
    *(uint2*)(out + i) = o;
  }
}

// ---------- W[K,N] fp32 -> Wt[N,K] bf16 ----------
__global__ void k_transpose(const float* __restrict__ W, u16* __restrict__ Wt, int K, int N) {
  __shared__ float tile[32][33];
  int x = threadIdx.x & 31, y = threadIdx.x >> 5;  // 256 threads: y in 0..7
  int n0 = blockIdx.x * 32, k0 = blockIdx.y * 32;
#pragma unroll
  for (int i = 0; i < 4; i++)
    tile[y + i * 8][x] = W[(size_t)(k0 + y + i * 8) * N + n0 + x];
  __syncthreads();
#pragma unroll
  for (int i = 0; i < 4; i++)
    Wt[(size_t)(n0 + y + i * 8) * K + k0 + x] = f2bf(tile[x][y + i * 8]);
}

// ---------- bf16 GEMM: C[M,N] = A[M,K] * Bt[N,K]^T + bias ----------
// modes: 0=Q (bf16 out [B,H,S,64], *scale)   1=K (f32 [B,KVH,S,64] + bf16 same)
//        2=V (f32 [B,KVH,S,64] + bf16 [B,KVH,64,S])   3=O (f32 [B,S,DM])
// grid: (M/128, N/128, z) -- z picks the 0/1 parameter set (used to fuse K+V)
__global__ __launch_bounds__(256) void k_gemm(
    const u16* __restrict__ A0, const u16* __restrict__ A1,
    const u16* __restrict__ B0, const u16* __restrict__ B1,
    const float* __restrict__ bias0, const float* __restrict__ bias1,
    float* __restrict__ f0, float* __restrict__ f1,
    u16* __restrict__ o0, u16* __restrict__ o1,
    int K, int mode0, int mode1, float scale) {
  const int z = blockIdx.z;
  const u16* A = z ? A1 : A0;
  const u16* Bt = z ? B1 : B0;
  const float* bias = z ? bias1 : bias0;
  float* outf = z ? f1 : f0;
  u16* outb = z ? o1 : o0;
  const int mode = z ? mode1 : mode0;

  __shared__ u16 lA[128 * 72];  // pad 64 -> 72 keeps ds_read_b128 ~2-way (free)
  __shared__ u16 lB[128 * 72];
  const int tid = threadIdx.x;
  const int lane = tid & 63, wave = tid >> 6;
  const int l15 = lane & 15, quad = lane >> 4;
  const int wm = wave >> 1, wn = wave & 1;
  const int m0 = blockIdx.x * 128, n0 = blockIdx.y * 128;
  const int sr = tid >> 3, scol = (tid & 7) * 8;

  f32x4 zero = {0.f, 0.f, 0.f, 0.f};
  f32x4 acc[4][4];
#pragma unroll
  for (int i = 0; i < 4; i++)
#pragma unroll
    for (int j = 0; j < 4; j++) acc[i][j] = zero;

  for (int k0 = 0; k0 < K; k0 += 64) {
#pragma unroll
    for (int rr = 0; rr < 4; rr++) {
      int r = sr + rr * 32;
      *(uint4*)&lA[r * 72 + scol] = *(const uint4*)(A + (size_t)(m0 + r) * K + k0 + scol);
      *(uint4*)&lB[r * 72 + scol] = *(const uint4*)(Bt + (size_t)(n0 + r) * K + k0 + scol);
    }
    __syncthreads();
    short8 af[4][2], bfr[4][2];
#pragma unroll
    for (int i = 0; i < 4; i++)
#pragma unroll
      for (int kb = 0; kb < 2; kb++) {
        af[i][kb] = *(const short8*)&lA[(wm * 64 + i * 16 + l15) * 72 + kb * 32 + quad * 8];
        bfr[i][kb] = *(const short8*)&lB[(wn * 64 + i * 16 + l15) * 72 + kb * 32 + quad * 8];
      }
#pragma unroll
    for (int i = 0; i < 4; i++)
#pragma unroll
      for (int j = 0; j < 4; j++) {
        acc[i][j] = MFMA16(af[i][0], bfr[j][0], acc[i][j]);
        acc[i][j] = MFMA16(af[i][1], bfr[j][1], acc[i][j]);
      }
    __syncthreads();
  }

  // epilogue: C/D layout col=lane&15, row=quad*4+reg  (m89-verified)
#pragma unroll
  for (int i = 0; i < 4; i++) {
    int rowg = m0 + wm * 64 + i * 16 + quad * 4;
#pragma unroll
    for (int j = 0; j < 4; j++) {
      int colg = n0 + wn * 64 + j * 16 + l15;
      float bv = bias[colg];
#pragma unroll
      for (int r = 0; r < 4; r++) {
        float v = acc[i][j][r] + bv;
        int rg = rowg + r;
        int b = rg >> 11, s = rg & 2047;
        if (mode == 0) {
          int h = colg >> 6, d = colg & 63;
          outb[(((size_t)(b * 16 + h) * SEQ + s) << 6) + d] = f2bf(v * scale);
        } else if (mode == 3) {
          outf[(size_t)rg * DM + colg] = v;
        } else {
          int kvh = colg >> 6, d = colg & 63;
          size_t idx = (((size_t)(b * 4 + kvh) * SEQ + s) << 6) + d;
          outf[idx] = v;
          if (mode == 1)
            outb[idx] = f2bf(v);
          else
            outb[((size_t)(b * 4 + kvh) * 64 + d) * SEQ + s] = f2bf(v);  // V^T
        }
      }
    }
  }
}

// ---------- flash attention ----------
// grid (S/128, B*H); 4 waves, each owns 32 q-rows; K-tiles of 64 keys.
// Q bf16 [B,H,S,64] (pre-scaled by 1/8), K bf16 [B,KVH,S,64], V^T bf16 [B,KVH,64,S]
__global__ __launch_bounds__(256) void k_flash(
    const u16* __restrict__ Qh, const u16* __restrict__ Kb,
    const u16* __restrict__ Vt, u16* __restrict__ ctx) {
  __shared__ u16 lK[64 * 72];
  __shared__ u16 lV[64 * 72];
  __shared__ u16 lP[4 * 32 * 72];
  const int tid = threadIdx.x;
  const int lane = tid & 63, wave = tid >> 6;
  const int l15 = lane & 15, quad = lane >> 4;
  const int bh = blockIdx.y;
  const int b = bh >> 4, h = bh & 15, kvh = h >> 2;
  const u16* Q = Qh + (size_t)bh * SEQ * 64;
  const u16* Kp = Kb + (size_t)(b * 4 + kvh) * SEQ * 64;
  const u16* Vp = Vt + (size_t)(b * 4 + kvh) * 64 * SEQ;
  const int q0 = blockIdx.x * 128 + wave * 32;

  // Q fragments stay in registers for the whole pass (A-layout: m=l15, k=quad*8+j)
  short8 qf[2][2];
#pragma unroll
  for (int mb = 0; mb < 2; mb++)
#pragma unroll
    for (int kb = 0; kb < 2; kb++)
      qf[mb][kb] = *(const short8*)(Q + (size_t)(q0 + mb * 16 + l15) * 64 + kb * 32 + quad * 8);

  f32x4 zero = {0.f, 0.f, 0.f, 0.f};
  f32x4 acc[2][4];
  float mrow[2][4], lrow[2][4];
#pragma unroll
  for (int mb = 0; mb < 2; mb++) {
#pragma unroll
    for (int nb = 0; nb < 4; nb++) acc[mb][nb] = zero;
#pragma unroll
    for (int r = 0; r < 4; r++) { mrow[mb][r] = -1e30f; lrow[mb][r] = 0.f; }
  }

  const int sr = tid >> 3, scol = (tid & 7) * 8;
  u16* lPw = lP + wave * (32 * 72);

  for (int k0 = 0; k0 < SEQ; k0 += 64) {
    __syncthreads();
    *(uint4*)&lK[sr * 72 + scol] = *(const uint4*)(Kp + (size_t)(k0 + sr) * 64 + scol);
    *(uint4*)&lK[(sr + 32) * 72 + scol] = *(const uint4*)(Kp + (size_t)(k0 + sr + 32) * 64 + scol);
    *(uint4*)&lV[sr * 72 + scol] = *(const uint4*)(Vp + (size_t)sr * SEQ + k0 + scol);
    *(uint4*)&lV[(sr + 32) * 72 + scol] = *(const uint4*)(Vp + (size_t)(sr + 32) * SEQ + k0 + scol);
    __syncthreads();

    // S = Q K^T  (already scaled via Q)
    f32x4 sc_[2][4];
#pragma unroll
    for (int nb = 0; nb < 4; nb++) {
      short8 kf0 = *(const short8*)&lK[(nb * 16 + l15) * 72 + quad * 8];
      short8 kf1 = *(const short8*)&lK[(nb * 16 + l15) * 72 + 32 + quad * 8];
#pragma unroll
      for (int mb = 0; mb < 2; mb++) {
        f32x4 t = zero;
        t = MFMA16(qf[mb][0], kf0, t);
        t = MFMA16(qf[mb][1], kf1, t);
        sc_[mb][nb] = t;
      }
    }

    // online softmax: row r of C lives in all 16 lanes of this quad
#pragma unroll
    for (int mb = 0; mb < 2; mb++) {
      float mx[4], al[4], sm[4];
#pragma unroll
      for (int r = 0; r < 4; r++)
        mx[r] = fmaxf(fmaxf(sc_[mb][0][r], sc_[mb][1][r]), fmaxf(sc_[mb][2][r], sc_[mb][3][r]));
#pragma unroll
      for (int off = 1; off < 16; off <<= 1)
#pragma unroll
        for (int r = 0; r < 4; r++) mx[r] = fmaxf(mx[r], __shfl_xor(mx[r], off));
#pragma unroll
      for (int r = 0; r < 4; r++) {
        float mn = fmaxf(mrow[mb][r], mx[r]);
        al[r] = __expf(mrow[mb][r] - mn);
        mrow[mb][r] = mn;
      }
#pragma unroll
      for (int nb = 0; nb < 4; nb++)
#pragma unroll
        for (int r = 0; r < 4; r++) sc_[mb][nb][r] = __expf(sc_[mb][nb][r] - mrow[mb][r]);
#pragma unroll
      for (int r = 0; r < 4; r++)
        sm[r] = (sc_[mb][0][r] + sc_[mb][1][r]) + (sc_[mb][2][r] + sc_[mb][3][r]);
#pragma unroll
      for (int off = 1; off < 16; off <<= 1)
#pragma unroll
        for (int r = 0; r < 4; r++) sm[r] += __shfl_xor(sm[r], off);
#pragma unroll
      for (int r = 0; r < 4; r++) lrow[mb][r] = lrow[mb][r] * al[r] + sm[r];
#pragma unroll
      for (int nb = 0; nb < 4; nb++)
#pragma unroll
        for (int r = 0; r < 4; r++) acc[mb][nb][r] *= al[r];
      // P: C-layout -> LDS [row][key] so it can re-enter as A-operand (m120 pattern)
#pragma unroll
      for (int nb = 0; nb < 4; nb++)
#pragma unroll
        for (int r = 0; r < 4; r++)
          lPw[(mb * 16 + quad * 4 + r) * 72 + nb * 16 + l15] = f2bf(sc_[mb][nb][r]);
    }
    __asm__ volatile("s_waitcnt lgkmcnt(0)" ::: "memory");  // wave-local LDS x-lane handoff

    // O += P V  (B-operand from V^T tile: n=d, k=key, contiguous)
#pragma unroll
    for (int kb = 0; kb < 2; kb++) {
      short8 vf[4];
#pragma unroll
      for (int nb = 0; nb < 4; nb++)
        vf[nb] = *(const short8*)&lV[(nb * 16 + l15) * 72 + kb * 32 + quad * 8];
#pragma unroll
      for (int mb = 0; mb < 2; mb++) {
        short8 pf = *(const short8*)&lPw[(mb * 16 + l15) * 72 + kb * 32 + quad * 8];
#pragma unroll
        for (int nb = 0; nb < 4; nb++) acc[mb][nb] = MFMA16(pf, vf[nb], acc[mb][nb]);
      }
    }
  }

  // epilogue: ctx bf16 [B,S,H*64] for the output GEMM
#pragma unroll
  for (int mb = 0; mb < 2; mb++) {
    float inv[4];
#pragma unroll
    for (int r = 0; r < 4; r++) inv[r] = 1.f / lrow[mb][r];
#pragma unroll
    for (int nb = 0; nb < 4; nb++)
#pragma unroll
      for (int r = 0; r < 4; r++) {
        int row = q0 + mb * 16 + quad * 4 + r;
        ctx[((size_t)(b * SEQ + row)) * DM + h * 64 + nb * 16 + l15] =
            f2bf(acc[mb][nb][r] * inv[r]);
      }
  }
}

extern "C" void kernel_launch(void* const* d_in, const int* in_sizes, int n_in,
                              void* d_out, int out_size, void* d_ws, size_t ws_size,
                              hipStream_t stream) {
  const float* query = (const float*)d_in[0];
  const float* key_in = (const float*)d_in[1];
  const float* value_in = (const float*)d_in[2];
  const float* Wq = (const float*)d_in[3];
  const float* bq = (const float*)d_in[4];
  const float* Wk = (const float*)d_in[5];
  const float* bk = (const float*)d_in[6];
  const float* Wv = (const float*)d_in[7];
  const float* bv = (const float*)d_in[8];
  const float* Wo = (const float*)d_in[9];
  const float* bo = (const float*)d_in[10];

  float* out = (float*)d_out;           // [B,S,DM] = 4194304
  float* outK = out + 4194304;          // [B,KVH,S,64] = 1048576
  float* outV = out + 5242880;          // [B,KVH,S,64] = 1048576

  char* ws = (char*)d_ws;
  u16* q_act = (u16*)(ws);                    // 8 MB  query bf16 [4096,1024]
  u16* k_act = (u16*)(ws + 8388608);          // 8 MB
  u16* v_act = (u16*)(ws + 16777216);         // 8 MB
  u16* WqT = (u16*)(ws + 25165824);           // 2 MB  [N=1024,K=1024]
  u16* WkT = (u16*)(ws + 27262976);           // 0.5 MB [256,1024]
  u16* WvT = (u16*)(ws + 27787264);           // 0.5 MB
  u16* WoT = (u16*)(ws + 28311552);           // 2 MB
  u16* qbf = (u16*)(ws + 30408704);           // 8 MB  Q bf16 [B,H,S,64] (scaled)
  u16* kbf = (u16*)(ws + 38797312);           // 2 MB  K bf16 [B,KVH,S,64]
  u16* vtb = (u16*)(ws + 40894464);           // 2 MB  V^T bf16 [B,KVH,64,S]
  u16* ctxb = (u16*)(ws + 42991616);          // 8 MB  ctx bf16 [B,S,DM]
  // total 51,380,224 bytes

  const int NACT = 2 * SEQ * DM;  // 4194304

  k_convert<<<1024, 256, 0, stream>>>(query, q_act, NACT);
  k_convert<<<1024, 256, 0, stream>>>(key_in, k_act, NACT);
  k_convert<<<1024, 256, 0, stream>>>(value_in, v_act, NACT);
  k_transpose<<<dim3(32, 32), 256, 0, stream>>>(Wq, WqT, 1024, 1024);
  k_transpose<<<dim3(8, 32), 256, 0, stream>>>(Wk, WkT, 1024, 256);
  k_transpose<<<dim3(8, 32), 256, 0, stream>>>(Wv, WvT, 1024, 256);
  k_transpose<<<dim3(32, 32), 256, 0, stream>>>(Wo, WoT, 1024, 1024);

  // Q projection (scale 1/sqrt(64) folded into bf16 Q)
  k_gemm<<<dim3(32, 8, 1), 256, 0, stream>>>(q_act, q_act, WqT, WqT, bq, bq,
                                             nullptr, nullptr, qbf, qbf,
                                             1024, 0, 0, 0.125f);
  // K and V projections fused via grid.z
  k_gemm<<<dim3(32, 2, 2), 256, 0, stream>>>(k_act, v_act, WkT, WvT, bk, bv,
                                             outK, outV, kbf, vtb,
                                             1024, 1, 2, 1.0f);
  // attention
  k_flash<<<dim3(16, 32), 256, 0, stream>>>(qbf, kbf, vtb, ctxb);
  // output projection
  k_gemm<<<dim3(32, 8, 1), 256, 0, stream>>>(ctxb, ctxb, WoT, WoT, bo, bo,
                                             out, out, nullptr, nullptr,
                                             1024, 3, 3, 1.0f);
}

// Round 2
// 248.926 us; speedup vs baseline: 1.3880x; 1.3880x over previous
//
#include <hip/hip_runtime.h>

typedef unsigned short u16;
typedef unsigned int u32;
typedef __attribute__((ext_vector_type(8))) short short8;
typedef __attribute__((ext_vector_type(4))) float f32x4;

#define MFMA16(a, b, c) __builtin_amdgcn_mfma_f32_16x16x32_bf16(a, b, c, 0, 0, 0)

// B=2, S=2048, D=1024, H=16, KVH=4, dk=64, G=4
#define SEQ 2048
#define DM 1024

__device__ __forceinline__ u16 f2bf(float f) {
  u32 u = __float_as_uint(f);
  u += 0x7fffu + ((u >> 16) & 1u);  // RNE
  return (u16)(u >> 16);
}
__device__ __forceinline__ u32 pack2(float a, float b) {
  return (u32)f2bf(a) | ((u32)f2bf(b) << 16);
}

// ---------- fused fp32 -> bf16 for the 3 activation tensors ----------
__global__ void k_convert3(const float* __restrict__ a, const float* __restrict__ b,
                           const float* __restrict__ c, u16* __restrict__ oa,
                           u16* __restrict__ ob, u16* __restrict__ oc, int n) {
  const float* in = blockIdx.y == 0 ? a : (blockIdx.y == 1 ? b : c);
  u16* out = blockIdx.y == 0 ? oa : (blockIdx.y == 1 ? ob : oc);
  for (int i = (blockIdx.x * 256 + threadIdx.x) * 4; i < n; i += gridDim.x * 256 * 4) {
    float4 f = *(const float4*)(in + i);
    uint2 o;
    o.x = pack2(f.x, f.y);
    o.y = pack2(f.z, f.w);
    *(uint2*)(out + i) = o;
  }
}

// ---------- fused W[K,N] fp32 -> Wt[N,K] bf16 for the 4 weights ----------
__global__ void k_transpose4(const float* __restrict__ Wq, const float* __restrict__ Wk,
                             const float* __restrict__ Wv, const float* __restrict__ Wo,
                             u16* __restrict__ WqT, u16* __restrict__ WkT,
                             u16* __restrict__ WvT, u16* __restrict__ WoT) {
  const int z = blockIdx.z;
  const float* W = z == 0 ? Wq : (z == 1 ? Wk : (z == 2 ? Wv : Wo));
  u16* Wt = z == 0 ? WqT : (z == 1 ? WkT : (z == 2 ? WvT : WoT));
  const int N = (z == 1 || z == 2) ? 256 : 1024;
  const int n0 = blockIdx.x * 32;
  if (n0 >= N) return;
  const int k0 = blockIdx.y * 32;
  __shared__ float tile[32][33];
  int x = threadIdx.x & 31, y = threadIdx.x >> 5;
#pragma unroll
  for (int i = 0; i < 4; i++)
    tile[y + i * 8][x] = W[(size_t)(k0 + y + i * 8) * N + n0 + x];
  __syncthreads();
#pragma unroll
  for (int i = 0; i < 4; i++)
    Wt[(size_t)(n0 + y + i * 8) * 1024 + k0 + x] = f2bf(tile[x][y + i * 8]);
}

// ---------- shared 128x128 bf16 GEMM core: acc = A[M,K] * Bt[N,K]^T ----------
__device__ __forceinline__ void gemm_core(const u16* __restrict__ A, const u16* __restrict__ Bt,
                                          int m0, int n0, int K, u16* lA, u16* lB,
                                          f32x4 acc[4][4]) {
  const int tid = threadIdx.x;
  const int lane = tid & 63, wave = tid >> 6;
  const int l15 = lane & 15, quad = lane >> 4;
  const int wm = wave >> 1, wn = wave & 1;
  const int sr = tid >> 3, scol = (tid & 7) * 8;
  f32x4 zero = {0.f, 0.f, 0.f, 0.f};
#pragma unroll
  for (int i = 0; i < 4; i++)
#pragma unroll
    for (int j = 0; j < 4; j++) acc[i][j] = zero;

  for (int k0 = 0; k0 < K; k0 += 64) {
#pragma unroll
    for (int rr = 0; rr < 4; rr++) {
      int r = sr + rr * 32;
      *(uint4*)&lA[r * 72 + scol] = *(const uint4*)(A + (size_t)(m0 + r) * K + k0 + scol);
      *(uint4*)&lB[r * 72 + scol] = *(const uint4*)(Bt + (size_t)(n0 + r) * K + k0 + scol);
    }
    __syncthreads();
    short8 af[4][2], bfr[4][2];
#pragma unroll
    for (int i = 0; i < 4; i++)
#pragma unroll
      for (int kb = 0; kb < 2; kb++) {
        af[i][kb] = *(const short8*)&lA[(wm * 64 + i * 16 + l15) * 72 + kb * 32 + quad * 8];
        bfr[i][kb] = *(const short8*)&lB[(wn * 64 + i * 16 + l15) * 72 + kb * 32 + quad * 8];
      }
#pragma unroll
    for (int i = 0; i < 4; i++)
#pragma unroll
      for (int j = 0; j < 4; j++) {
        acc[i][j] = MFMA16(af[i][0], bfr[j][0], acc[i][j]);
        acc[i][j] = MFMA16(af[i][1], bfr[j][1], acc[i][j]);
      }
    __syncthreads();
  }
}

// ---------- fused Q/K/V projection GEMM ----------
// grid (32, 12): y<8 -> Q tile y; y in {8,9} -> K tile y-8; y in {10,11} -> V tile y-10
__global__ __launch_bounds__(256) void k_proj(
    const u16* __restrict__ qa, const u16* __restrict__ ka, const u16* __restrict__ va,
    const u16* __restrict__ WqT, const u16* __restrict__ WkT, const u16* __restrict__ WvT,
    const float* __restrict__ bq, const float* __restrict__ bk, const float* __restrict__ bv,
    u16* __restrict__ qbf, float* __restrict__ outK, u16* __restrict__ kbf,
    float* __restrict__ outV, u16* __restrict__ vtb, float qscale) {
  __shared__ u16 lA[128 * 72];
  __shared__ u16 lB[128 * 72];
  const int by = blockIdx.y;
  const u16 *A, *Bt;
  const float* bias;
  int n0, mode;
  if (by < 8) { A = qa; Bt = WqT; bias = bq; n0 = by * 128; mode = 0; }
  else if (by < 10) { A = ka; Bt = WkT; bias = bk; n0 = (by - 8) * 128; mode = 1; }
  else { A = va; Bt = WvT; bias = bv; n0 = (by - 10) * 128; mode = 2; }
  const int m0 = blockIdx.x * 128;

  f32x4 acc[4][4];
  gemm_core(A, Bt, m0, n0, 1024, lA, lB, acc);

  const int lane = threadIdx.x & 63, wave = threadIdx.x >> 6;
  const int l15 = lane & 15, quad = lane >> 4;
  const int wm = wave >> 1, wn = wave & 1;
#pragma unroll
  for (int i = 0; i < 4; i++) {
    int rowg = m0 + wm * 64 + i * 16 + quad * 4;
#pragma unroll
    for (int j = 0; j < 4; j++) {
      int colg = n0 + wn * 64 + j * 16 + l15;
      float bv_ = bias[colg];
#pragma unroll
      for (int r = 0; r < 4; r++) {
        float v = acc[i][j][r] + bv_;
        int rg = rowg + r;
        int b = rg >> 11, s = rg & 2047;
        if (mode == 0) {
          int h = colg >> 6, d = colg & 63;
          qbf[(((size_t)(b * 16 + h) * SEQ + s) << 6) + d] = f2bf(v * qscale);
        } else {
          int kvh = colg >> 6, d = colg & 63;
          size_t idx = (((size_t)(b * 4 + kvh) * SEQ + s) << 6) + d;
          if (mode == 1) {
            outK[idx] = v;
            kbf[idx] = f2bf(v);
          } else {
            outV[idx] = v;
            vtb[((size_t)(b * 4 + kvh) * 64 + d) * SEQ + s] = f2bf(v);  // V^T
          }
        }
      }
    }
  }
}

// ---------- output projection GEMM ----------
__global__ __launch_bounds__(256) void k_out(const u16* __restrict__ ctxb,
                                             const u16* __restrict__ WoT,
                                             const float* __restrict__ bo,
                                             float* __restrict__ out) {
  __shared__ u16 lA[128 * 72];
  __shared__ u16 lB[128 * 72];
  const int m0 = blockIdx.x * 128, n0 = blockIdx.y * 128;
  f32x4 acc[4][4];
  gemm_core(ctxb, WoT, m0, n0, 1024, lA, lB, acc);

  const int lane = threadIdx.x & 63, wave = threadIdx.x >> 6;
  const int l15 = lane & 15, quad = lane >> 4;
  const int wm = wave >> 1, wn = wave & 1;
#pragma unroll
  for (int i = 0; i < 4; i++) {
    int rowg = m0 + wm * 64 + i * 16 + quad * 4;
#pragma unroll
    for (int j = 0; j < 4; j++) {
      int colg = n0 + wn * 64 + j * 16 + l15;
      float bv_ = bo[colg];
#pragma unroll
      for (int r = 0; r < 4; r++)
        out[(size_t)(rowg + r) * DM + colg] = acc[i][j][r] + bv_;
    }
  }
}

// ---------- flash attention (S^T formulation) ----------
// grid (S/64, B*H); 2 waves x 32 q-rows. K-tiles of 64 keys.
// S^T = K·Q^T so softmax axis = C rows; each lane owns ONE query (col=l15).
// Q bf16 [B,H,S,64] (pre-scaled by log2e/8), K bf16 [B,KVH,S,64], V^T bf16 [B,KVH,64,S]
__global__ __launch_bounds__(128, 3) void k_flash(
    const u16* __restrict__ Qh, const u16* __restrict__ Kb,
    const u16* __restrict__ Vt, u16* __restrict__ ctx) {
  __shared__ u16 lK[64 * 72];
  __shared__ u16 lV[64 * 72];
  __shared__ u16 lP[2 * 32 * 72];
  const int tid = threadIdx.x;
  const int lane = tid & 63, wave = tid >> 6;
  const int l15 = lane & 15, quad = lane >> 4;
  const int bh = blockIdx.y;
  const int b = bh >> 4, h = bh & 15, kvh = h >> 2;
  const u16* Q = Qh + (size_t)bh * SEQ * 64;
  const u16* Kp = Kb + (size_t)(b * 4 + kvh) * SEQ * 64;
  const u16* Vp = Vt + (size_t)(b * 4 + kvh) * 64 * SEQ;
  const int q0 = blockIdx.x * 64 + wave * 32;

  // Q fragments in registers all pass (B-operand: n=l15, k=quad*8+j)
  short8 qf[2][2];
#pragma unroll
  for (int mb = 0; mb < 2; mb++)
#pragma unroll
    for (int kb = 0; kb < 2; kb++)
      qf[mb][kb] = *(const short8*)(Q + (size_t)(q0 + mb * 16 + l15) * 64 + kb * 32 + quad * 8);

  f32x4 zero = {0.f, 0.f, 0.f, 0.f};
  f32x4 acc[2][4];  // O^T: acc[mb][d-block], C-layout row=d_local, col=q=l15
  float m_[2] = {-1e30f, -1e30f}, l_[2] = {0.f, 0.f};
#pragma unroll
  for (int mb = 0; mb < 2; mb++)
#pragma unroll
    for (int nb = 0; nb < 4; nb++) acc[mb][nb] = zero;

  const int sr = tid >> 3, scol = (tid & 7) * 8;
  u16* lPw = lP + wave * (32 * 72);

  for (int k0 = 0; k0 < SEQ; k0 += 64) {
    __syncthreads();
#pragma unroll
    for (int i = 0; i < 4; i++) {
      int r = sr + i * 16;
      *(uint4*)&lK[r * 72 + scol] = *(const uint4*)(Kp + (size_t)(k0 + r) * 64 + scol);
      *(uint4*)&lV[r * 72 + scol] = *(const uint4*)(Vp + (size_t)r * SEQ + k0 + scol);
    }
    __syncthreads();

    // S^T tiles: rows = keys (quad*4+r), cols = q (l15)
    f32x4 sc[2][4];
#pragma unroll
    for (int nb = 0; nb < 4; nb++) {
      short8 kf0 = *(const short8*)&lK[(nb * 16 + l15) * 72 + quad * 8];
      short8 kf1 = *(const short8*)&lK[(nb * 16 + l15) * 72 + 32 + quad * 8];
#pragma unroll
      for (int mb = 0; mb < 2; mb++) {
        f32x4 t = zero;
        t = MFMA16(kf0, qf[mb][0], t);
        t = MFMA16(kf1, qf[mb][1], t);
        sc[mb][nb] = t;
      }
    }

    // online softmax in exp2 domain; per-lane scalar state (one q per lane)
#pragma unroll
    for (int mb = 0; mb < 2; mb++) {
      float mx = sc[mb][0][0];
#pragma unroll
      for (int nb = 0; nb < 4; nb++)
#pragma unroll
        for (int r = 0; r < 4; r++) mx = fmaxf(mx, sc[mb][nb][r]);
      mx = fmaxf(mx, __shfl_xor(mx, 16));
      mx = fmaxf(mx, __shfl_xor(mx, 32));
      float mn = fmaxf(m_[mb], mx);
      float al = __builtin_amdgcn_exp2f(m_[mb] - mn);
      m_[mb] = mn;
      float sum = 0.f;
#pragma unroll
      for (int nb = 0; nb < 4; nb++)
#pragma unroll
        for (int r = 0; r < 4; r++) {
          float v = __builtin_amdgcn_exp2f(sc[mb][nb][r] - mn);
          sc[mb][nb][r] = v;
          sum += v;
        }
      sum += __shfl_xor(sum, 16);
      sum += __shfl_xor(sum, 32);
      l_[mb] = l_[mb] * al + sum;
#pragma unroll
      for (int nb = 0; nb < 4; nb++) {
        acc[mb][nb] *= al;
        // P stored [q][key]: 4 consecutive keys per lane -> one b64 write (min-aliased @72)
        uint2 p;
        p.x = pack2(sc[mb][nb][0], sc[mb][nb][1]);
        p.y = pack2(sc[mb][nb][2], sc[mb][nb][3]);
        *(uint2*)&lPw[(mb * 16 + l15) * 72 + nb * 16 + quad * 4] = p;
      }
    }
    __asm__ volatile("s_waitcnt lgkmcnt(0)" ::: "memory");  // wave-local LDS handoff

    // O^T += V^T · P^T   (A = V^T tile [d][key], B = P [q][key])
#pragma unroll
    for (int kb = 0; kb < 2; kb++) {
      short8 vfr[4];
#pragma unroll
      for (int nb = 0; nb < 4; nb++)
        vfr[nb] = *(const short8*)&lV[(nb * 16 + l15) * 72 + kb * 32 + quad * 8];
#pragma unroll
      for (int mb = 0; mb < 2; mb++) {
        short8 pf = *(const short8*)&lPw[(mb * 16 + l15) * 72 + kb * 32 + quad * 8];
#pragma unroll
        for (int nb = 0; nb < 4; nb++) acc[mb][nb] = MFMA16(vfr[nb], pf, acc[mb][nb]);
      }
    }
  }

  // epilogue: lane holds q=q0+mb*16+l15, d = nb*16+quad*4+{0..3} -> packed 8B stores
#pragma unroll
  for (int mb = 0; mb < 2; mb++) {
    float inv = __builtin_amdgcn_rcpf(l_[mb]);
    int q = q0 + mb * 16 + l15;
    u16* base = ctx + ((size_t)(b * SEQ + q)) * DM + h * 64;
#pragma unroll
    for (int nb = 0; nb < 4; nb++) {
      uint2 o;
      o.x = pack2(acc[mb][nb][0] * inv, acc[mb][nb][1] * inv);
      o.y = pack2(acc[mb][nb][2] * inv, acc[mb][nb][3] * inv);
      *(uint2*)(base + nb * 16 + quad * 4) = o;
    }
  }
}

extern "C" void kernel_launch(void* const* d_in, const int* in_sizes, int n_in,
                              void* d_out, int out_size, void* d_ws, size_t ws_size,
                              hipStream_t stream) {
  const float* query = (const float*)d_in[0];
  const float* key_in = (const float*)d_in[1];
  const float* value_in = (const float*)d_in[2];
  const float* Wq = (const float*)d_in[3];
  const float* bq = (const float*)d_in[4];
  const float* Wk = (const float*)d_in[5];
  const float* bk = (const float*)d_in[6];
  const float* Wv = (const float*)d_in[7];
  const float* bv = (const float*)d_in[8];
  const float* Wo = (const float*)d_in[9];
  const float* bo = (const float*)d_in[10];

  float* out = (float*)d_out;   // [B,S,DM]
  float* outK = out + 4194304;  // [B,KVH,S,64]
  float* outV = out + 5242880;  // [B,KVH,S,64]

  char* ws = (char*)d_ws;
  u16* q_act = (u16*)(ws);
  u16* k_act = (u16*)(ws + 8388608);
  u16* v_act = (u16*)(ws + 16777216);
  u16* WqT = (u16*)(ws + 25165824);
  u16* WkT = (u16*)(ws + 27262976);
  u16* WvT = (u16*)(ws + 27787264);
  u16* WoT = (u16*)(ws + 28311552);
  u16* qbf = (u16*)(ws + 30408704);   // Q bf16 [B,H,S,64], pre-scaled log2e/8
  u16* kbf = (u16*)(ws + 38797312);   // K bf16 [B,KVH,S,64]
  u16* vtb = (u16*)(ws + 40894464);   // V^T bf16 [B,KVH,64,S]
  u16* ctxb = (u16*)(ws + 42991616);  // ctx bf16 [B,S,DM]

  const int NACT = 2 * SEQ * DM;
  const float qscale = 0.125f * 1.44269504088896340736f;  // fold log2(e) -> exp2 softmax

  k_convert3<<<dim3(1024, 3), 256, 0, stream>>>(query, key_in, value_in, q_act, k_act, v_act,
                                                NACT);
  k_transpose4<<<dim3(32, 32, 4), 256, 0, stream>>>(Wq, Wk, Wv, Wo, WqT, WkT, WvT, WoT);
  k_proj<<<dim3(32, 12), 256, 0, stream>>>(q_act, k_act, v_act, WqT, WkT, WvT, bq, bk, bv,
                                           qbf, outK, kbf, outV, vtb, qscale);
  k_flash<<<dim3(32, 32), 128, 0, stream>>>(qbf, kbf, vtb, ctxb);
  k_out<<<dim3(32, 8), 256, 0, stream>>>(ctxb, WoT, bo, out);
}